// Round 1
// baseline (274.240 us; speedup 1.0000x reference)
//
#include <hip/hip_runtime.h>
#include <hip/hip_bf16.h>

#define NUM_GENES 4384
#define GPAD 4480        // 35 * 128 (pad resident dim)
#define DM 128
#define ROWB 256         // bytes per bf16 row (128*2)
#define LDS_STRIDE 272   // 256 + 16B pad -> 4-way b128 (structural floor)
#define NTILES 137       // 4384 / 32 (stream dim is exact)
#define NCHUNK 4
#define TILES_PER_CHUNK 35

typedef __attribute__((ext_vector_type(8))) short short8;
typedef __attribute__((ext_vector_type(16))) float floatx16;

__global__ void zero_lw(float* l, float* w) {
    int i = blockIdx.x * 256 + threadIdx.x;   // 140 blocks * 256 = 35840 = 8*4480
    l[i] = 0.f;
    w[i] = 0.f;
}

// Q = (mut @ W_in + b_in) * 1/sqrt(128), cast to bf16; pad rows zeroed.
__global__ void prep_q(const float* __restrict__ mut, const float* __restrict__ W_in,
                       const float* __restrict__ b_in, __hip_bfloat16* __restrict__ Qb) {
    int idx = blockIdx.x * 256 + threadIdx.x;     // 8*4480*128 = 17920 blocks
    int d = idx & 127;
    int g = (idx >> 7) % GPAD;
    int b = idx / (GPAD * 128);
    float v = 0.f;
    if (g < NUM_GENES) {
        const float* m = mut + ((size_t)b * NUM_GENES + g) * 4;
        v = b_in[d] + m[0] * W_in[d] + m[1] * W_in[128 + d]
                    + m[2] * W_in[256 + d] + m[3] * W_in[384 + d];
        v *= 0.088388347648318447f;   // 1/sqrt(128), folded so exp(S) needs no scale
    }
    Qb[idx] = __float2bfloat16(v);
}

__global__ void prep_k(const float* __restrict__ key, __hip_bfloat16* __restrict__ Kb) {
    int idx = blockIdx.x * 256 + threadIdx.x;     // 4480*128 = 2240 blocks
    int g = idx >> 7;
    float v = (g < NUM_GENES) ? key[idx] : 0.f;
    Kb[idx] = __float2bfloat16(v);
}

__global__ void recip_k(float* l) {
    int i = blockIdx.x * 256 + threadIdx.x;       // 140 blocks
    l[i] = 1.0f / l[i];
}

// Unified phase kernel.
// PB=false (phase A): resident = Q rows (per b), stream = K tiles, out = l[b,q] += rowsum(exp(S))
// PB=true  (phase B): resident = K rows, stream = Q tiles (per b), out = w[b,k] += rowsum(exp(S)*linv[col])
// MFMA: D[m][n] = sum_d A[m][d] * B[d][n]; A frag = resident row (lane&31), B frag = streamed row (lane&31),
// both read 16B at byte offset dsl*32 + (lane>>5)*16 of a 256B row.
// C/D layout: col = lane&31, row = (reg&3) + 8*(reg>>2) + 4*(lane>>5).
template <bool PB>
__global__ __launch_bounds__(256)
void phase_kernel(const __hip_bfloat16* __restrict__ Qb,
                  const __hip_bfloat16* __restrict__ Kb,
                  const float* __restrict__ linv,
                  float* __restrict__ out) {
    __shared__ __align__(16) char tile[32 * LDS_STRIDE];

    int rb    = blockIdx.x;   // resident 128-row block, 0..34
    int chunk = blockIdx.y;   // 0..3 over stream tiles
    int b     = blockIdx.z;   // batch

    const char* resident = (const char*)(PB ? Kb : (Qb + (size_t)b * GPAD * DM));
    const char* stream   = (const char*)(PB ? (Qb + (size_t)b * GPAD * DM) : Kb);

    int t = threadIdx.x;
    int lane = t & 63, wid = t >> 6;
    int m = lane & 31, half = lane >> 5;

    // Resident A fragments: 32 rows per wave, held in VGPRs for the whole loop.
    short8 afrag[8];
    const char* arow = resident + (size_t)(rb * 128 + wid * 32 + m) * ROWB;
#pragma unroll
    for (int dsl = 0; dsl < 8; ++dsl)
        afrag[dsl] = *(const short8*)(arow + dsl * 32 + half * 16);

    float lacc[16];
#pragma unroll
    for (int r = 0; r < 16; ++r) lacc[r] = 0.f;

    int t0 = chunk * TILES_PER_CHUNK;
    int t1 = min(NTILES, t0 + TILES_PER_CHUNK);
    int sr = t >> 3, sc = t & 7;   // staging: thread -> (row, 32B chunk)

    for (int kt = t0; kt < t1; ++kt) {
        const char* src = stream + (size_t)(kt * 32 + sr) * ROWB + sc * 32;
        float4 v0 = *(const float4*)src;
        float4 v1 = *(const float4*)(src + 16);
        __syncthreads();   // previous iteration's LDS reads done
        char* dst = tile + sr * LDS_STRIDE + sc * 32;
        *(float4*)dst = v0;
        *(float4*)(dst + 16) = v1;
        __syncthreads();

        floatx16 acc;
#pragma unroll
        for (int r = 0; r < 16; ++r) acc[r] = 0.f;
#pragma unroll
        for (int dsl = 0; dsl < 8; ++dsl) {
            short8 bfrag = *(const short8*)(tile + m * LDS_STRIDE + dsl * 32 + half * 16);
            acc = __builtin_amdgcn_mfma_f32_32x32x16_bf16(afrag[dsl], bfrag, acc, 0, 0, 0);
        }

        float scl = 1.0f;
        if (PB) scl = linv[b * GPAD + kt * 32 + m];   // col = streamed q index
#pragma unroll
        for (int r = 0; r < 16; ++r)
            lacc[r] += __expf(acc[r]) * scl;
    }

    // Reduce across the 32 columns (lanes sharing the same 'half').
#pragma unroll
    for (int off = 1; off <= 16; off <<= 1) {
#pragma unroll
        for (int r = 0; r < 16; ++r)
            lacc[r] += __shfl_xor(lacc[r], off, 64);
    }

    if (m == 0) {   // lanes 0 and 32 hold sums for rows (+0 / +4)
        float* ob = out + b * GPAD + rb * 128 + wid * 32 + 4 * half;
#pragma unroll
        for (int r = 0; r < 16; ++r) {
            int row = (r & 3) + 8 * (r >> 2);
            atomicAdd(ob + row, lacc[r]);
        }
    }
}

// mean = (w/G) @ V ; h = gelu(mean@W1+b1) ; out = h@W2+b2
__global__ void finish_k(const float* __restrict__ w, const float* __restrict__ V,
                         const float* __restrict__ W1, const float* __restrict__ b1,
                         const float* __restrict__ W2, const float* __restrict__ b2,
                         float* __restrict__ out) {
    int b = blockIdx.x, t = threadIdx.x;
    int d = t & 127, half = t >> 7;   // split k-range in two
    const float* wb = w + b * GPAD + half * 2192;
    const float* Vp = V + (size_t)(half * 2192) * 128 + d;
    float a0 = 0, a1 = 0, a2 = 0, a3 = 0;
    for (int k = 0; k < 2192; k += 4) {
        a0 += wb[k]     * Vp[(size_t)k * 128];
        a1 += wb[k + 1] * Vp[(size_t)(k + 1) * 128];
        a2 += wb[k + 2] * Vp[(size_t)(k + 2) * 128];
        a3 += wb[k + 3] * Vp[(size_t)(k + 3) * 128];
    }
    __shared__ float red[256];
    __shared__ float smean[128];
    __shared__ float sh[64];
    red[t] = (a0 + a1) + (a2 + a3);
    __syncthreads();
    if (t < 128) smean[t] = (red[t] + red[t + 128]) * (1.0f / 4384.0f);
    __syncthreads();
    if (t < 64) {
        float s = b1[t];
        for (int dd = 0; dd < 128; ++dd) s += smean[dd] * W1[dd * 64 + t];
        sh[t] = 0.5f * s * (1.0f + erff(s * 0.70710678118654752f));   // exact gelu
    }
    __syncthreads();
    if (t < 26) {
        float s = b2[t];
        for (int j = 0; j < 64; ++j) s += sh[j] * W2[j * 26 + t];
        out[b * 26 + t] = s;
    }
}

extern "C" void kernel_launch(void* const* d_in, const int* in_sizes, int n_in,
                              void* d_out, int out_size, void* d_ws, size_t ws_size,
                              hipStream_t stream) {
    const float* mut  = (const float*)d_in[0];   // [8,4384,4]
    const float* V    = (const float*)d_in[1];   // [4384,128]
    const float* W_in = (const float*)d_in[2];   // [4,128]
    const float* b_in = (const float*)d_in[3];   // [128]
    const float* key  = (const float*)d_in[4];   // [4384,128]
    const float* W1   = (const float*)d_in[5];   // [128,64]
    const float* b1   = (const float*)d_in[6];   // [64]
    const float* W2   = (const float*)d_in[7];   // [64,26]
    const float* b2   = (const float*)d_in[8];   // [26]
    float* out = (float*)d_out;                  // [8,26]

    char* ws = (char*)d_ws;
    __hip_bfloat16* Qb = (__hip_bfloat16*)(ws);                    // 8*4480*128*2 = 9,175,040
    __hip_bfloat16* Kb = (__hip_bfloat16*)(ws + 9175040);          // 4480*128*2   = 1,146,880
    float* lbuf        = (float*)(ws + 10321920);                  // 8*4480*4     =   143,360
    float* wbuf        = (float*)(ws + 10465280);                  // 8*4480*4     =   143,360

    zero_lw<<<140, 256, 0, stream>>>(lbuf, wbuf);
    prep_q<<<17920, 256, 0, stream>>>(mut, W_in, b_in, Qb);
    prep_k<<<2240, 256, 0, stream>>>(key, Kb);

    dim3 grid(35, NCHUNK, 8);
    phase_kernel<false><<<grid, 256, 0, stream>>>(Qb, Kb, lbuf, lbuf);  // l = rowsum exp(QK^T)
    recip_k<<<140, 256, 0, stream>>>(lbuf);                             // l -> 1/l
    phase_kernel<true><<<grid, 256, 0, stream>>>(Qb, Kb, lbuf, wbuf);   // w = colsum softmax

    finish_k<<<8, 256, 0, stream>>>(wbuf, V, W1, b1, W2, b2, out);
}

// Round 2
// 246.506 us; speedup vs baseline: 1.1125x; 1.1125x over previous
//
#include <hip/hip_runtime.h>
#include <hip/hip_bf16.h>

#define NUM_GENES 4384
#define GPAD 4480        // 35 * 128 (pad resident dim)
#define DM 128
#define ROWB 256         // bytes per bf16 row (128*2)
#define LDS_STRIDE 272   // 256 + 16B pad -> 4-way b128 (structural floor)
#define NTILES 137       // 4384 / 32 (stream dim is exact)
#define NCHUNK 4
#define TILES_PER_CHUNK 35

typedef __attribute__((ext_vector_type(8))) short short8;
typedef __attribute__((ext_vector_type(16))) float floatx16;

__global__ void zero_lw(float* l, float* w, float* meanbuf) {
    int i = blockIdx.x * 256 + threadIdx.x;   // 140 blocks * 256 = 35840 = 8*4480
    l[i] = 0.f;
    w[i] = 0.f;
    if (i < 1024) meanbuf[i] = 0.f;           // 8*128
}

// Q = (mut @ W_in + b_in) * 1/sqrt(128), cast to bf16; pad rows zeroed.
__global__ void prep_q(const float* __restrict__ mut, const float* __restrict__ W_in,
                       const float* __restrict__ b_in, __hip_bfloat16* __restrict__ Qb) {
    int idx = blockIdx.x * 256 + threadIdx.x;     // 8*4480*128 = 17920 blocks
    int d = idx & 127;
    int g = (idx >> 7) % GPAD;
    int b = idx / (GPAD * 128);
    float v = 0.f;
    if (g < NUM_GENES) {
        const float* m = mut + ((size_t)b * NUM_GENES + g) * 4;
        v = b_in[d] + m[0] * W_in[d] + m[1] * W_in[128 + d]
                    + m[2] * W_in[256 + d] + m[3] * W_in[384 + d];
        v *= 0.088388347648318447f;   // 1/sqrt(128), folded so exp(S) needs no scale
    }
    Qb[idx] = __float2bfloat16(v);
}

__global__ void prep_k(const float* __restrict__ key, __hip_bfloat16* __restrict__ Kb) {
    int idx = blockIdx.x * 256 + threadIdx.x;     // 4480*128 = 2240 blocks
    int g = idx >> 7;
    float v = (g < NUM_GENES) ? key[idx] : 0.f;
    Kb[idx] = __float2bfloat16(v);
}

__global__ void recip_k(float* l) {
    int i = blockIdx.x * 256 + threadIdx.x;       // 140 blocks
    l[i] = 1.0f / l[i];
}

// Unified phase kernel.
// PB=false (phase A): resident = Q rows (per b), stream = K tiles, out = l[b,q] += rowsum(exp(S))
// PB=true  (phase B): resident = K rows, stream = Q tiles (per b), out = w[b,k] += rowsum(exp(S)*linv[col])
// MFMA: D[m][n] = sum_d A[m][d] * B[d][n]; A frag = resident row (lane&31), B frag = streamed row (lane&31),
// both read 16B at byte offset dsl*32 + (lane>>5)*16 of a 256B row.
// C/D layout: col = lane&31, row = (reg&3) + 8*(reg>>2) + 4*(lane>>5).
template <bool PB>
__global__ __launch_bounds__(256)
void phase_kernel(const __hip_bfloat16* __restrict__ Qb,
                  const __hip_bfloat16* __restrict__ Kb,
                  const float* __restrict__ linv,
                  float* __restrict__ out) {
    __shared__ __align__(16) char tile[32 * LDS_STRIDE];

    int rb    = blockIdx.x;   // resident 128-row block, 0..34
    int chunk = blockIdx.y;   // 0..3 over stream tiles
    int b     = blockIdx.z;   // batch

    const char* resident = (const char*)(PB ? Kb : (Qb + (size_t)b * GPAD * DM));
    const char* stream   = (const char*)(PB ? (Qb + (size_t)b * GPAD * DM) : Kb);

    int t = threadIdx.x;
    int lane = t & 63, wid = t >> 6;
    int m = lane & 31, half = lane >> 5;

    // Resident A fragments: 32 rows per wave, held in VGPRs for the whole loop.
    short8 afrag[8];
    const char* arow = resident + (size_t)(rb * 128 + wid * 32 + m) * ROWB;
#pragma unroll
    for (int dsl = 0; dsl < 8; ++dsl)
        afrag[dsl] = *(const short8*)(arow + dsl * 32 + half * 16);

    float lacc[16];
#pragma unroll
    for (int r = 0; r < 16; ++r) lacc[r] = 0.f;

    int t0 = chunk * TILES_PER_CHUNK;
    int t1 = min(NTILES, t0 + TILES_PER_CHUNK);
    int sr = t >> 3, sc = t & 7;   // staging: thread -> (row, 32B chunk)

    for (int kt = t0; kt < t1; ++kt) {
        const char* src = stream + (size_t)(kt * 32 + sr) * ROWB + sc * 32;
        float4 v0 = *(const float4*)src;
        float4 v1 = *(const float4*)(src + 16);
        __syncthreads();   // previous iteration's LDS reads done
        char* dst = tile + sr * LDS_STRIDE + sc * 32;
        *(float4*)dst = v0;
        *(float4*)(dst + 16) = v1;
        __syncthreads();

        floatx16 acc;
#pragma unroll
        for (int r = 0; r < 16; ++r) acc[r] = 0.f;
#pragma unroll
        for (int dsl = 0; dsl < 8; ++dsl) {
            short8 bfrag = *(const short8*)(tile + m * LDS_STRIDE + dsl * 32 + half * 16);
            acc = __builtin_amdgcn_mfma_f32_32x32x16_bf16(afrag[dsl], bfrag, acc, 0, 0, 0);
        }

        float scl = 1.0f;
        if (PB) scl = linv[b * GPAD + kt * 32 + m];   // col = streamed q index
#pragma unroll
        for (int r = 0; r < 16; ++r)
            lacc[r] += __expf(acc[r]) * scl;
    }

    // Reduce across the 32 columns (lanes sharing the same 'half').
#pragma unroll
    for (int off = 1; off <= 16; off <<= 1) {
#pragma unroll
        for (int r = 0; r < 16; ++r)
            lacc[r] += __shfl_xor(lacc[r], off, 64);
    }

    if (m == 0) {   // lanes 0 and 32 hold sums for rows (+0 / +4)
        float* ob = out + b * GPAD + rb * 128 + wid * 32 + 4 * half;
#pragma unroll
        for (int r = 0; r < 16; ++r) {
            int row = (r & 3) + 8 * (r >> 2);
            atomicAdd(ob + row, lacc[r]);
        }
    }
}

// mean partials: meanbuf[b,d] += sum_{g in block's 128 rows} w[b,g] * V[g,d]
// grid (35, 8), block 256. V is 2.24 MB -> L2/L3 resident across the sweep.
__global__ __launch_bounds__(256)
void mean_k(const float* __restrict__ w, const float* __restrict__ V,
            float* __restrict__ meanbuf) {
    int rb = blockIdx.x, b = blockIdx.y;
    int t = threadIdx.x;
    int d = t & 127, half = t >> 7;        // each half-block covers 64 gene rows
    int g0 = rb * 128 + half * 64;
    int nv = NUM_GENES - g0;               // valid rows in this half (can be <=0)
    if (nv > 64) nv = 64;
    float a = 0.f;
    if (nv > 0) {
        const float* wb = w + b * GPAD + g0;
        const float* Vp = V + (size_t)g0 * 128 + d;
        for (int k = 0; k < nv; ++k)
            a += wb[k] * Vp[(size_t)k * 128];
    }
    atomicAdd(meanbuf + b * 128 + d, a);
}

// h = gelu(mean/G @ W1 + b1) ; out = h@W2 + b2.  grid 8, block 64.
__global__ void mlp_k(const float* __restrict__ meanbuf,
                      const float* __restrict__ W1, const float* __restrict__ b1,
                      const float* __restrict__ W2, const float* __restrict__ b2,
                      float* __restrict__ out) {
    int b = blockIdx.x, t = threadIdx.x;
    __shared__ float sh[64];
    const float* mb = meanbuf + b * 128;
    float s = b1[t];
    for (int d = 0; d < 128; ++d)
        s += (mb[d] * (1.0f / 4384.0f)) * W1[d * 64 + t];
    sh[t] = 0.5f * s * (1.0f + erff(s * 0.70710678118654752f));   // exact gelu
    __syncthreads();
    if (t < 26) {
        float o = b2[t];
        for (int j = 0; j < 64; ++j) o += sh[j] * W2[j * 26 + t];
        out[b * 26 + t] = o;
    }
}

extern "C" void kernel_launch(void* const* d_in, const int* in_sizes, int n_in,
                              void* d_out, int out_size, void* d_ws, size_t ws_size,
                              hipStream_t stream) {
    const float* mut  = (const float*)d_in[0];   // [8,4384,4]
    const float* V    = (const float*)d_in[1];   // [4384,128]
    const float* W_in = (const float*)d_in[2];   // [4,128]
    const float* b_in = (const float*)d_in[3];   // [128]
    const float* key  = (const float*)d_in[4];   // [4384,128]
    const float* W1   = (const float*)d_in[5];   // [128,64]
    const float* b1   = (const float*)d_in[6];   // [64]
    const float* W2   = (const float*)d_in[7];   // [64,26]
    const float* b2   = (const float*)d_in[8];   // [26]
    float* out = (float*)d_out;                  // [8,26]

    char* ws = (char*)d_ws;
    __hip_bfloat16* Qb = (__hip_bfloat16*)(ws);                    // 8*4480*128*2 = 9,175,040
    __hip_bfloat16* Kb = (__hip_bfloat16*)(ws + 9175040);          // 4480*128*2   = 1,146,880
    float* lbuf        = (float*)(ws + 10321920);                  // 8*4480*4     =   143,360
    float* wbuf        = (float*)(ws + 10465280);                  // 8*4480*4     =   143,360
    float* meanbuf     = (float*)(ws + 10608640);                  // 8*128*4      =     4,096

    zero_lw<<<140, 256, 0, stream>>>(lbuf, wbuf, meanbuf);
    prep_q<<<17920, 256, 0, stream>>>(mut, W_in, b_in, Qb);
    prep_k<<<2240, 256, 0, stream>>>(key, Kb);

    dim3 grid(35, NCHUNK, 8);
    phase_kernel<false><<<grid, 256, 0, stream>>>(Qb, Kb, lbuf, lbuf);  // l = rowsum exp(QK^T)
    recip_k<<<140, 256, 0, stream>>>(lbuf);                             // l -> 1/l
    phase_kernel<true><<<grid, 256, 0, stream>>>(Qb, Kb, lbuf, wbuf);   // w = colsum softmax

    mean_k<<<dim3(35, 8), 256, 0, stream>>>(wbuf, V, meanbuf);
    mlp_k<<<8, 64, 0, stream>>>(meanbuf, W1, b1, W2, b2, out);
}

// Round 3
// 227.021 us; speedup vs baseline: 1.2080x; 1.0858x over previous
//
#include <hip/hip_runtime.h>
#include <hip/hip_bf16.h>

#define NUM_GENES 4384
#define GPAD 4608        // 18 * 256 (pad resident dim; 256 rows per block)
#define DM 128
#define ROWB 256         // bytes per bf16 row (128*2)
#define LDS_STRIDE 272   // 256 + 16B pad
#define NTILES 137       // 4384 / 32 (stream dim is exact, no pad streamed)
#define RB_BLOCKS 18     // GPAD / 256
#define NCHUNK 6
#define TPC 23           // ceil(137/6); last chunk gets 22

typedef __attribute__((ext_vector_type(8))) short short8;
typedef __attribute__((ext_vector_type(16))) float floatx16;

#if defined(__has_builtin)
#  if __has_builtin(__builtin_amdgcn_exp2f)
#    define FAST_EXP2(x) __builtin_amdgcn_exp2f(x)
#  endif
#endif
#ifndef FAST_EXP2
#  define FAST_EXP2(x) exp2f(x)
#endif

__global__ void zero_lw(float* l, float* w, float* meanbuf) {
    int i = blockIdx.x * 256 + threadIdx.x;   // 144 blocks * 256 = 36864 = 8*4608
    l[i] = 0.f;
    w[i] = 0.f;
    if (i < 1024) meanbuf[i] = 0.f;           // 8*128
}

// Q = (mut @ W_in + b_in) * log2(e)/sqrt(128), cast to bf16; pad rows zeroed.
// log2(e) folded so the phase kernels use a bare exp2 (single v_exp_f32).
__global__ void prep_q(const float* __restrict__ mut, const float* __restrict__ W_in,
                       const float* __restrict__ b_in, __hip_bfloat16* __restrict__ Qb) {
    int idx = blockIdx.x * 256 + threadIdx.x;     // 18432 blocks
    int d = idx & 127;
    int g = (idx >> 7) % GPAD;
    int b = idx / (GPAD * 128);
    float v = 0.f;
    if (g < NUM_GENES) {
        const float* m = mut + ((size_t)b * NUM_GENES + g) * 4;
        v = b_in[d] + m[0] * W_in[d] + m[1] * W_in[128 + d]
                    + m[2] * W_in[256 + d] + m[3] * W_in[384 + d];
        v *= (0.08838834764831845f * 1.4426950408889634f);   // scale * log2(e)
    }
    Qb[idx] = __float2bfloat16(v);
}

__global__ void prep_k(const float* __restrict__ key, __hip_bfloat16* __restrict__ Kb) {
    int idx = blockIdx.x * 256 + threadIdx.x;     // 2304 blocks
    int g = idx >> 7;
    float v = (g < NUM_GENES) ? key[idx] : 0.f;
    Kb[idx] = __float2bfloat16(v);
}

__global__ void recip_k(float* l) {
    int i = blockIdx.x * 256 + threadIdx.x;       // 144 blocks
    l[i] = 1.0f / l[i];
}

// Unified phase kernel, 64 resident rows per wave (2 MFMAs per B fragment).
// PB=false: resident=Q (per b), stream=K, out l[b,q] += rowsum(exp2(S))
// PB=true : resident=K, stream=Q (per b), out w[b,k] += rowsum(exp2(S)*linv[q])
// A/B frag: lane holds row/col (lane&31), 16B at byte dsl*32 + (lane>>5)*16.
// C/D: col=lane&31, row=(r&3)+8*(r>>2)+4*(lane>>5).
template <bool PB>
__global__ __launch_bounds__(256)
void phase_kernel(const __hip_bfloat16* __restrict__ Qb,
                  const __hip_bfloat16* __restrict__ Kb,
                  const float* __restrict__ linv,
                  float* __restrict__ out) {
    __shared__ __align__(16) char tile[32 * LDS_STRIDE];

    int rb    = blockIdx.x;   // resident 256-row block, 0..17
    int chunk = blockIdx.y;   // 0..5 over stream tiles
    int b     = blockIdx.z;   // batch

    const char* resident = (const char*)(PB ? Kb : (Qb + (size_t)b * GPAD * DM));
    const char* stream   = (const char*)(PB ? (Qb + (size_t)b * GPAD * DM) : Kb);

    int t = threadIdx.x;
    int lane = t & 63, wid = t >> 6;
    int m = lane & 31, half = lane >> 5;

    // Resident A fragments: 64 rows per wave (two 32-row groups), in VGPRs.
    short8 afrag[2][8];
#pragma unroll
    for (int g = 0; g < 2; ++g) {
        const char* arow = resident + (size_t)(rb * 256 + wid * 64 + g * 32 + m) * ROWB;
#pragma unroll
        for (int dsl = 0; dsl < 8; ++dsl)
            afrag[g][dsl] = *(const short8*)(arow + dsl * 32 + half * 16);
    }

    float lacc[2][16];
#pragma unroll
    for (int g = 0; g < 2; ++g)
#pragma unroll
        for (int r = 0; r < 16; ++r) lacc[g][r] = 0.f;

    int t0 = chunk * TPC;
    int t1 = min(NTILES, t0 + TPC);
    int sr = t >> 3, sc = t & 7;   // staging: thread -> (row, 32B chunk)
    char* dst = tile + sr * LDS_STRIDE + sc * 32;

    // Prefetch first tile into registers.
    const char* src = stream + (size_t)(t0 * 32 + sr) * ROWB + sc * 32;
    float4 v0 = *(const float4*)src;
    float4 v1 = *(const float4*)(src + 16);

    for (int kt = t0; kt < t1; ++kt) {
        __syncthreads();             // previous iteration's LDS reads done
        *(float4*)dst = v0;
        *(float4*)(dst + 16) = v1;
        __syncthreads();

        if (kt + 1 < t1) {           // prefetch next tile during compute
            const char* s2 = stream + (size_t)((kt + 1) * 32 + sr) * ROWB + sc * 32;
            v0 = *(const float4*)s2;
            v1 = *(const float4*)(s2 + 16);
        }

        floatx16 acc0, acc1;
#pragma unroll
        for (int r = 0; r < 16; ++r) { acc0[r] = 0.f; acc1[r] = 0.f; }
#pragma unroll
        for (int dsl = 0; dsl < 8; ++dsl) {
            short8 bfrag = *(const short8*)(tile + m * LDS_STRIDE + dsl * 32 + half * 16);
            acc0 = __builtin_amdgcn_mfma_f32_32x32x16_bf16(afrag[0][dsl], bfrag, acc0, 0, 0, 0);
            acc1 = __builtin_amdgcn_mfma_f32_32x32x16_bf16(afrag[1][dsl], bfrag, acc1, 0, 0, 0);
        }

        if (PB) {
            float scl = linv[b * GPAD + kt * 32 + m];   // col = streamed q index
#pragma unroll
            for (int r = 0; r < 16; ++r) {
                lacc[0][r] = fmaf(FAST_EXP2(acc0[r]), scl, lacc[0][r]);
                lacc[1][r] = fmaf(FAST_EXP2(acc1[r]), scl, lacc[1][r]);
            }
        } else {
#pragma unroll
            for (int r = 0; r < 16; ++r) {
                lacc[0][r] += FAST_EXP2(acc0[r]);
                lacc[1][r] += FAST_EXP2(acc1[r]);
            }
        }
    }

    // Reduce across the 32 columns (lanes sharing the same 'half').
#pragma unroll
    for (int off = 1; off <= 16; off <<= 1)
#pragma unroll
        for (int g = 0; g < 2; ++g)
#pragma unroll
            for (int r = 0; r < 16; ++r)
                lacc[g][r] += __shfl_xor(lacc[g][r], off, 64);

    if (m == 0) {   // lanes 0 and 32 hold sums for rows (+0 / +4)
#pragma unroll
        for (int g = 0; g < 2; ++g) {
            float* ob = out + b * GPAD + rb * 256 + wid * 64 + g * 32 + 4 * half;
#pragma unroll
            for (int r = 0; r < 16; ++r)
                atomicAdd(ob + (r & 3) + 8 * (r >> 2), lacc[g][r]);
        }
    }
}

// mean partials: meanbuf[b,d] += sum_{g in block's 128 rows} w[b,g] * V[g,d]
__global__ __launch_bounds__(256)
void mean_k(const float* __restrict__ w, const float* __restrict__ V,
            float* __restrict__ meanbuf) {
    int rb = blockIdx.x, b = blockIdx.y;
    int t = threadIdx.x;
    int d = t & 127, half = t >> 7;        // each half-block covers 64 gene rows
    int g0 = rb * 128 + half * 64;
    int nv = NUM_GENES - g0;               // valid rows in this half (can be <=0)
    if (nv > 64) nv = 64;
    float a = 0.f;
    if (nv > 0) {
        const float* wb = w + b * GPAD + g0;
        const float* Vp = V + (size_t)g0 * 128 + d;
        for (int k = 0; k < nv; ++k)
            a += wb[k] * Vp[(size_t)k * 128];
    }
    atomicAdd(meanbuf + b * 128 + d, a);
}

// h = gelu(mean/G @ W1 + b1) ; out = h@W2 + b2.  grid 8, block 64.
__global__ void mlp_k(const float* __restrict__ meanbuf,
                      const float* __restrict__ W1, const float* __restrict__ b1,
                      const float* __restrict__ W2, const float* __restrict__ b2,
                      float* __restrict__ out) {
    int b = blockIdx.x, t = threadIdx.x;
    __shared__ float sh[64];
    const float* mb = meanbuf + b * 128;
    float s = b1[t];
    for (int d = 0; d < 128; ++d)
        s += (mb[d] * (1.0f / 4384.0f)) * W1[d * 64 + t];
    sh[t] = 0.5f * s * (1.0f + erff(s * 0.70710678118654752f));   // exact gelu
    __syncthreads();
    if (t < 26) {
        float o = b2[t];
        for (int j = 0; j < 64; ++j) o += sh[j] * W2[j * 26 + t];
        out[b * 26 + t] = o;
    }
}

extern "C" void kernel_launch(void* const* d_in, const int* in_sizes, int n_in,
                              void* d_out, int out_size, void* d_ws, size_t ws_size,
                              hipStream_t stream) {
    const float* mut  = (const float*)d_in[0];   // [8,4384,4]
    const float* V    = (const float*)d_in[1];   // [4384,128]
    const float* W_in = (const float*)d_in[2];   // [4,128]
    const float* b_in = (const float*)d_in[3];   // [128]
    const float* key  = (const float*)d_in[4];   // [4384,128]
    const float* W1   = (const float*)d_in[5];   // [128,64]
    const float* b1   = (const float*)d_in[6];   // [64]
    const float* W2   = (const float*)d_in[7];   // [64,26]
    const float* b2   = (const float*)d_in[8];   // [26]
    float* out = (float*)d_out;                  // [8,26]

    char* ws = (char*)d_ws;
    __hip_bfloat16* Qb = (__hip_bfloat16*)(ws);                    // 8*4608*128*2 = 9,437,184
    __hip_bfloat16* Kb = (__hip_bfloat16*)(ws + 9437184);          // 4608*128*2   = 1,179,648
    float* lbuf        = (float*)(ws + 10616832);                  // 8*4608*4     =   147,456
    float* wbuf        = (float*)(ws + 10764288);                  // 8*4608*4     =   147,456
    float* meanbuf     = (float*)(ws + 10911744);                  // 8*128*4      =     4,096

    zero_lw<<<144, 256, 0, stream>>>(lbuf, wbuf, meanbuf);
    prep_q<<<18432, 256, 0, stream>>>(mut, W_in, b_in, Qb);
    prep_k<<<2304, 256, 0, stream>>>(key, Kb);

    dim3 grid(RB_BLOCKS, NCHUNK, 8);
    phase_kernel<false><<<grid, 256, 0, stream>>>(Qb, Kb, lbuf, lbuf);  // l = rowsum exp2(S)
    recip_k<<<144, 256, 0, stream>>>(lbuf);                             // l -> 1/l
    phase_kernel<true><<<grid, 256, 0, stream>>>(Qb, Kb, lbuf, wbuf);   // w = colsum softmax

    mean_k<<<dim3(35, 8), 256, 0, stream>>>(wbuf, V, meanbuf);
    mlp_k<<<8, 64, 0, stream>>>(meanbuf, W1, b1, W2, b2, out);
}